// Round 2
// baseline (473.132 us; speedup 1.0000x reference)
//
#include <hip/hip_runtime.h>
#include <cstdint>
#include <cstddef>

#ifndef NEG_SLOPE
#define NEG_SLOPE 0.2f
#endif

// ---------------------------------------------------------------------------
// K0: detect whether edge_index is stored as int64 (low/high int32 pairs) or
// int32. Values are node ids in [0, 50000) so int64 high words are all zero.
// If the first 16 odd int32 words are all zero -> int64 layout.
// ---------------------------------------------------------------------------
__global__ void detect_kernel(const int* __restrict__ ei, int* __restrict__ flag) {
    if (threadIdx.x == 0 && blockIdx.x == 0) {
        int orv = 0;
#pragma unroll
        for (int k = 0; k < 16; ++k) orv |= ei[2 * k + 1];
        *flag = (orv == 0) ? 1 : 0;
    }
}

// K1: deg[i] = 1 (self loop)
__global__ void init_deg_kernel(int* __restrict__ deg, int n) {
    int i = blockIdx.x * blockDim.x + threadIdx.x;
    if (i < n) deg[i] = 1;
}

// K2: count in-degrees
__global__ void count_kernel(const int* __restrict__ ei, int E,
                             int* __restrict__ deg, const int* __restrict__ flag) {
    int is64 = *flag;
    int stride = gridDim.x * blockDim.x;
    for (int e = blockIdx.x * blockDim.x + threadIdx.x; e < E; e += stride) {
        int dst = is64 ? ei[2 * ((long)E + e)] : ei[E + e];
        atomicAdd(&deg[dst], 1);
    }
}

// K3: exclusive scan deg -> off (single block, wave-scan based)
__global__ __launch_bounds__(1024) void scan_kernel(const int* __restrict__ deg,
                                                    int* __restrict__ off, int n) {
    __shared__ int wsum[16];
    __shared__ int carry_s;
    int t = threadIdx.x;
    int lane = t & 63, wid = t >> 6;
    if (t == 0) carry_s = 0;
    __syncthreads();
    for (int base = 0; base < n; base += 1024) {
        int idx = base + t;
        int v = (idx < n) ? deg[idx] : 0;
        int inc = v;
#pragma unroll
        for (int d = 1; d < 64; d <<= 1) {
            int o = __shfl_up(inc, d, 64);
            if (lane >= d) inc += o;
        }
        if (lane == 63) wsum[wid] = inc;
        __syncthreads();
        int carry = carry_s;
        int wpre = 0;
        for (int w = 0; w < wid; ++w) wpre += wsum[w];
        if (idx < n) off[idx] = carry + wpre + inc - v;
        __syncthreads();
        if (t == 1023) carry_s = carry + wpre + inc;
    }
    __syncthreads();
    if (t == 0) off[n] = carry_s;
}

// K4: place self-loop at the head of each node's bucket, init cursor
__global__ void selfloop_kernel(const int* __restrict__ off, int* __restrict__ cursor,
                                int* __restrict__ csr, int n) {
    int i = blockIdx.x * blockDim.x + threadIdx.x;
    if (i < n) {
        int o = off[i];
        csr[o] = i;
        cursor[i] = o + 1;
    }
}

// K5: scatter edges into CSR buckets (store src id)
__global__ void fill_kernel(const int* __restrict__ ei, int E,
                            int* __restrict__ cursor, int* __restrict__ csr,
                            const int* __restrict__ flag) {
    int is64 = *flag;
    int stride = gridDim.x * blockDim.x;
    for (int e = blockIdx.x * blockDim.x + threadIdx.x; e < E; e += stride) {
        int src = is64 ? ei[2 * (long)e] : ei[e];
        int dst = is64 ? ei[2 * ((long)E + e)] : ei[E + e];
        int slot = atomicAdd(&cursor[dst], 1);
        csr[slot] = src;
    }
}

// ---------------------------------------------------------------------------
// K6: h = X @ W^T, alpha_s = h @ a_src, alpha_d = h @ a_dst  (fused)
// One wave per node; lane j computes h[i][j]. W staged in LDS, row stride
// IN_DIM+4 floats -> balanced 8-accesses/bank for float4 reads.
// ---------------------------------------------------------------------------
template <int IN_DIM>
__global__ __launch_bounds__(256) void gemm_alpha_kernel(
    const float* __restrict__ X, const float* __restrict__ W,
    const float* __restrict__ a_src, const float* __restrict__ a_dst,
    float* __restrict__ H, float* __restrict__ AS, float* __restrict__ AD, int n) {
    constexpr int LDW = IN_DIM + 4;
    __shared__ float sW[64 * LDW];
    int t = threadIdx.x;
    for (int idx = t; idx < 64 * IN_DIM; idx += 256) {
        int r = idx / IN_DIM, c = idx - r * IN_DIM;
        sW[r * LDW + c] = W[idx];
    }
    __syncthreads();
    int lane = t & 63, wid = t >> 6;
    float asj = a_src[lane], adj = a_dst[lane];
    const float* wrow = &sW[lane * LDW];
    int wave = blockIdx.x * 4 + wid;
    int nw = gridDim.x * 4;
    for (int i = wave; i < n; i += nw) {
        const float* xr = X + (size_t)i * IN_DIM;
        float acc = 0.f;
#pragma unroll
        for (int k = 0; k < IN_DIM; k += 4) {
            float4 xv = *reinterpret_cast<const float4*>(xr + k);    // same addr all lanes (broadcast)
            float4 wv = *reinterpret_cast<const float4*>(wrow + k);  // LDS, balanced banks
            acc += xv.x * wv.x + xv.y * wv.y + xv.z * wv.z + xv.w * wv.w;
        }
        H[(size_t)i * 64 + lane] = acc;
        float c1 = acc * asj, c2 = acc * adj;
#pragma unroll
        for (int d = 32; d >= 1; d >>= 1) {
            c1 += __shfl_xor(c1, d, 64);
            c2 += __shfl_xor(c2, d, 64);
        }
        if (lane == 0) {
            AS[i] = c1;
            AD[i] = c2;
        }
    }
}

// ---------------------------------------------------------------------------
// K7: per-destination-node softmax + aggregation. One wave per node.
// Pass A: lane-parallel online softmax (max + rescaled sum) over edges.
// Pass B: lane j owns output component j; edge coefficients redistributed
// via __shfl (no scratch round-trip, no atomics).
// ---------------------------------------------------------------------------
template <bool RELU>
__global__ __launch_bounds__(256) void aggregate_kernel(
    const float* __restrict__ AS, const float* __restrict__ AD,
    const float* __restrict__ H, const int* __restrict__ off,
    const int* __restrict__ csr, const float* __restrict__ bias,
    float* __restrict__ out, int n) {
    int lane = threadIdx.x & 63, wid = threadIdx.x >> 6;
    int i = blockIdx.x * 4 + wid;
    if (i >= n) return;
    int s = off[i], e = off[i + 1];
    float ad = AD[i];

    // Pass A: online max / sum
    float m = -1e30f, ssum = 0.f;
    for (int k = s + lane; k < e; k += 64) {
        int sc = csr[k];
        float ev = AS[sc] + ad;
        ev = ev > 0.f ? ev : NEG_SLOPE * ev;
        float nm = fmaxf(m, ev);
        ssum = ssum * __expf(m - nm) + __expf(ev - nm);
        m = nm;
    }
#pragma unroll
    for (int d = 32; d >= 1; d >>= 1) {
        float om = __shfl_xor(m, d, 64);
        float os = __shfl_xor(ssum, d, 64);
        float nm = fmaxf(m, om);
        ssum = ssum * __expf(m - nm) + os * __expf(om - nm);
        m = nm;
    }
    float inv = 1.0f / ssum;

    // Pass B: aggregate; chunk edges 64 at a time, redistribute via shfl
    float acc = 0.f;
    for (int kb = s; kb < e; kb += 64) {
        int k = kb + lane;
        float ev = -1e30f;
        int sc = 0;
        if (k < e) {
            sc = csr[k];
            ev = AS[sc] + ad;
            ev = ev > 0.f ? ev : NEG_SLOPE * ev;
        }
        float p = __expf(ev - m) * inv;  // 0 for OOB lanes
        int cnt = min(64, e - kb);
        for (int u = 0; u < cnt; ++u) {
            float coef = __shfl(p, u, 64);
            int scu = __shfl(sc, u, 64);
            acc += coef * H[(size_t)scu * 64 + lane];  // coalesced 256B row
        }
    }
    acc += bias[lane];
    if (RELU) acc = fmaxf(acc, 0.f);
    out[(size_t)i * 64 + lane] = acc;
}

// ---------------------------------------------------------------------------
extern "C" void kernel_launch(void* const* d_in, const int* in_sizes, int n_in,
                              void* d_out, int out_size, void* d_ws, size_t ws_size,
                              hipStream_t stream) {
    const float* x   = (const float*)d_in[0];
    const int*   ei  = (const int*)d_in[1];
    const float* W1  = (const float*)d_in[2];
    const float* a1s = (const float*)d_in[3];
    const float* a1d = (const float*)d_in[4];
    const float* b1  = (const float*)d_in[5];
    const float* W2  = (const float*)d_in[6];
    const float* a2s = (const float*)d_in[7];
    const float* a2d = (const float*)d_in[8];
    const float* b2  = (const float*)d_in[9];
    float* out = (float*)d_out;

    int n = in_sizes[0] / 128;
    int E = in_sizes[1] / 2;
    int ET = E + n;

    char* ws = (char*)d_ws;
    size_t o = 0;
    auto alloc = [&](size_t bytes) {
        void* p = ws + o;
        o += (bytes + 255) & ~(size_t)255;
        return p;
    };
    int*   flag   = (int*)alloc(4);
    int*   deg    = (int*)alloc((size_t)n * 4);
    int*   off    = (int*)alloc(((size_t)n + 1) * 4);
    int*   cursor = (int*)alloc((size_t)n * 4);
    int*   csr    = (int*)alloc((size_t)ET * 4);
    float* h1     = (float*)alloc((size_t)n * 64 * 4);
    float* as1    = (float*)alloc((size_t)n * 4);
    float* ad1    = (float*)alloc((size_t)n * 4);
    float* hr1    = (float*)alloc((size_t)n * 64 * 4);
    float* as2    = (float*)alloc((size_t)n * 4);
    float* ad2    = (float*)alloc((size_t)n * 4);
    (void)ws_size; (void)n_in; (void)out_size;

    int nb256 = (n + 255) / 256;

    detect_kernel<<<1, 64, 0, stream>>>(ei, flag);
    init_deg_kernel<<<nb256, 256, 0, stream>>>(deg, n);
    count_kernel<<<2048, 256, 0, stream>>>(ei, E, deg, flag);
    scan_kernel<<<1, 1024, 0, stream>>>(deg, off, n);
    selfloop_kernel<<<nb256, 256, 0, stream>>>(off, cursor, csr, n);
    fill_kernel<<<2048, 256, 0, stream>>>(ei, E, cursor, csr, flag);

    // Layer 1
    gemm_alpha_kernel<128><<<2048, 256, 0, stream>>>(x, W1, a1s, a1d, h1, as1, ad1, n);
    aggregate_kernel<true><<<(n + 3) / 4, 256, 0, stream>>>(as1, ad1, h1, off, csr, b1, hr1, n);

    // Layer 2 (reuse h1 as h2)
    gemm_alpha_kernel<64><<<2048, 256, 0, stream>>>(hr1, W2, a2s, a2d, h1, as2, ad2, n);
    aggregate_kernel<false><<<(n + 3) / 4, 256, 0, stream>>>(as2, ad2, h1, off, csr, b2, out, n);
}